// Round 1
// baseline (215.425 us; speedup 1.0000x reference)
//
#include <hip/hip_runtime.h>
#include <hip/hip_bf16.h>

typedef __attribute__((ext_vector_type(8))) short short8;
typedef __attribute__((ext_vector_type(4))) float f32x4;

#define LOG2E 1.44269504088896340736f

__device__ __forceinline__ unsigned short f2bf_rn(float x) {
    unsigned u = __builtin_bit_cast(unsigned, x);
    u += 0x7fffu + ((u >> 16) & 1u);
    return (unsigned short)(u >> 16);
}
__device__ __forceinline__ float bf2f(unsigned short h) {
    unsigned u = ((unsigned)h) << 16;
    return __builtin_bit_cast(float, u);
}

// Grid: 448 blocks = 14 (b,t) * 32 q-blocks of 128. Block: 256 threads (4 waves).
// Each wave: 32 queries (2 M-tiles of 16). K-tiles of 64 keys staged in LDS as
// bf16 hi/lo (split-precision 3-MFMA QK^T). Online softmax in base-2 domain.
__global__ __launch_bounds__(256) void kast_attn_kernel(
    const float* __restrict__ K,   // (2,8,4096,64)
    const float* __restrict__ V,   // (2,8,4096,3)
    const float* __restrict__ MK,  // (2,7,1024,64)
    const float* __restrict__ MV,  // (2,7,1024,3)
    float* __restrict__ OUT)       // (2,7,4096,3)
{
    __shared__ alignas(16) unsigned short sKhi[64][64];
    __shared__ alignas(16) unsigned short sKlo[64][64];
    __shared__ alignas(16) float sV[64][4];

    const int id = blockIdx.x;
    // XCD-chunked swizzle (448 % 8 == 0 -> bijective)
    const int sw = (id & 7) * 56 + (id >> 3);
    const int bt = sw >> 5;       // 0..13
    const int qblk = sw & 31;     // 0..31
    const int b = bt / 7, t = bt % 7;

    const int tid = threadIdx.x;
    const int lane = tid & 63;
    const int w = tid >> 6;       // wave 0..3
    const int col = lane & 15;    // MFMA col / B-row selector
    const int g = lane >> 4;      // k-chunk group, also C-row group

    // ---- Load Q fragments (A operand), scaled by log2(e), split hi/lo ----
    const float* Qbase = K + (((size_t)b * 8 + (t + 1)) * 4096) * 64;
    short8 ah[2][2], al[2][2];
#pragma unroll
    for (int mt = 0; mt < 2; ++mt) {
        const int qrow = qblk * 128 + w * 32 + mt * 16 + col;
        const float* qp = Qbase + (size_t)qrow * 64;
#pragma unroll
        for (int ch = 0; ch < 2; ++ch) {
            const int c0 = ch * 32 + g * 8;
            short8 h, l;
#pragma unroll
            for (int i = 0; i < 8; ++i) {
                float x = qp[c0 + i] * LOG2E;
                unsigned short hb = f2bf_rn(x);
                h[i] = (short)hb;
                l[i] = (short)f2bf_rn(x - bf2f(hb));
            }
            ah[mt][ch] = h;
            al[mt][ch] = l;
        }
    }

    float outacc[2][4][3];
#pragma unroll
    for (int mt = 0; mt < 2; ++mt)
#pragma unroll
        for (int j = 0; j < 4; ++j) {
            outacc[mt][j][0] = 0.f; outacc[mt][j][1] = 0.f; outacc[mt][j][2] = 0.f;
        }

    for (int phase = 0; phase < 2; ++phase) {
        const float* kp; const float* vp; int ntile; float wgt;
        if (phase == 0) {
            kp = K + (((size_t)b * 8 + t) * 4096) * 64;
            vp = V + (((size_t)b * 8 + t) * 4096) * 3;
            ntile = 64; wgt = 0.8f;
        } else {
            kp = MK + (((size_t)b * 7 + t) * 1024) * 64;
            vp = MV + (((size_t)b * 7 + t) * 1024) * 3;
            ntile = 16; wgt = 0.2f;
        }

        float mrun[2] = {-1e30f, -1e30f};
        float lsum[2][4] = {{0.f,0.f,0.f,0.f},{0.f,0.f,0.f,0.f}};
        float racc[2][4][3];
#pragma unroll
        for (int mt = 0; mt < 2; ++mt)
#pragma unroll
            for (int j = 0; j < 4; ++j) {
                racc[mt][j][0] = 0.f; racc[mt][j][1] = 0.f; racc[mt][j][2] = 0.f;
            }

        for (int kt = 0; kt < ntile; ++kt) {
            // ---- Stage K tile (64x64 f32 -> bf16 hi/lo, XOR-swizzled) ----
            {
                const int r = tid >> 2;            // 0..63
                const int c0 = (tid & 3) * 16;     // 0,16,32,48
                const float* src = kp + ((size_t)(kt * 64 + r)) * 64 + c0;
                const f32x4* s4 = (const f32x4*)src;
                const int rs = (r & 7) << 3;
#pragma unroll
                for (int half = 0; half < 2; ++half) {
                    f32x4 xa = s4[half * 2 + 0];
                    f32x4 xb = s4[half * 2 + 1];
                    short8 h, l;
#pragma unroll
                    for (int i = 0; i < 4; ++i) {
                        float x = xa[i];
                        unsigned short hb = f2bf_rn(x);
                        h[i] = (short)hb;
                        l[i] = (short)f2bf_rn(x - bf2f(hb));
                    }
#pragma unroll
                    for (int i = 0; i < 4; ++i) {
                        float x = xb[i];
                        unsigned short hb = f2bf_rn(x);
                        h[4 + i] = (short)hb;
                        l[4 + i] = (short)f2bf_rn(x - bf2f(hb));
                    }
                    const int cc = (c0 + half * 8) ^ rs;
                    *(short8*)&sKhi[r][cc] = h;
                    *(short8*)&sKlo[r][cc] = l;
                }
                if (tid < 192) {
                    const unsigned vr = (unsigned)tid / 3u;
                    const unsigned vd = (unsigned)tid - vr * 3u;
                    sV[vr][vd] = vp[(size_t)(kt * 64) * 3 + tid];
                }
            }
            __syncthreads();

            // ---- QK^T via split-bf16 MFMA (3 products) ----
            f32x4 acc[2][4];
#pragma unroll
            for (int mt = 0; mt < 2; ++mt)
#pragma unroll
                for (int nt = 0; nt < 4; ++nt) acc[mt][nt] = (f32x4){0.f, 0.f, 0.f, 0.f};

#pragma unroll
            for (int ch = 0; ch < 2; ++ch) {
                short8 bh[4], bl[4];
#pragma unroll
                for (int nt = 0; nt < 4; ++nt) {
                    const int rr = nt * 16 + col;
                    const int cc = (ch * 32 + g * 8) ^ ((rr & 7) << 3);
                    bh[nt] = *(const short8*)&sKhi[rr][cc];
                    bl[nt] = *(const short8*)&sKlo[rr][cc];
                }
#pragma unroll
                for (int mt = 0; mt < 2; ++mt)
#pragma unroll
                    for (int nt = 0; nt < 4; ++nt) {
                        acc[mt][nt] = __builtin_amdgcn_mfma_f32_16x16x32_bf16(ah[mt][ch], bh[nt], acc[mt][nt], 0, 0, 0);
                        acc[mt][nt] = __builtin_amdgcn_mfma_f32_16x16x32_bf16(ah[mt][ch], bl[nt], acc[mt][nt], 0, 0, 0);
                        acc[mt][nt] = __builtin_amdgcn_mfma_f32_16x16x32_bf16(al[mt][ch], bh[nt], acc[mt][nt], 0, 0, 0);
                    }
            }

            // ---- Online softmax + PV accumulate ----
#pragma unroll
            for (int mt = 0; mt < 2; ++mt) {
                // block max over this lane's 16 scores, then across the 16-lane col group
                float tm = acc[mt][0][0];
#pragma unroll
                for (int nt = 0; nt < 4; ++nt)
#pragma unroll
                    for (int j = 0; j < 4; ++j) tm = fmaxf(tm, acc[mt][nt][j]);
                tm = fmaxf(tm, __shfl_xor(tm, 1, 16));
                tm = fmaxf(tm, __shfl_xor(tm, 2, 16));
                tm = fmaxf(tm, __shfl_xor(tm, 4, 16));
                tm = fmaxf(tm, __shfl_xor(tm, 8, 16));

                if (!__all(tm <= mrun[mt])) {
                    const float mnew = fmaxf(mrun[mt], tm);
                    const float scale = __builtin_amdgcn_exp2f(mrun[mt] - mnew);
#pragma unroll
                    for (int j = 0; j < 4; ++j) {
                        lsum[mt][j] *= scale;
                        racc[mt][j][0] *= scale;
                        racc[mt][j][1] *= scale;
                        racc[mt][j][2] *= scale;
                    }
                    mrun[mt] = mnew;
                }

#pragma unroll
                for (int nt = 0; nt < 4; ++nt) {
                    const int rr = nt * 16 + col;
                    const f32x4 vv = *(const f32x4*)&sV[rr][0];
#pragma unroll
                    for (int j = 0; j < 4; ++j) {
                        const float p = __builtin_amdgcn_exp2f(acc[mt][nt][j] - mrun[mt]);
                        lsum[mt][j] += p;
                        racc[mt][j][0] += p * vv[0];
                        racc[mt][j][1] += p * vv[1];
                        racc[mt][j][2] += p * vv[2];
                    }
                }
            }
            __syncthreads();
        }

        // ---- Finalize phase: reduce across the 16 key-col lanes ----
#pragma unroll
        for (int mt = 0; mt < 2; ++mt)
#pragma unroll
            for (int j = 0; j < 4; ++j) {
                float ls = lsum[mt][j];
                float r0 = racc[mt][j][0];
                float r1 = racc[mt][j][1];
                float r2 = racc[mt][j][2];
#pragma unroll
                for (int off = 1; off < 16; off <<= 1) {
                    ls += __shfl_xor(ls, off, 16);
                    r0 += __shfl_xor(r0, off, 16);
                    r1 += __shfl_xor(r1, off, 16);
                    r2 += __shfl_xor(r2, off, 16);
                }
                const float s = wgt / ls;
                outacc[mt][j][0] += r0 * s;
                outacc[mt][j][1] += r1 * s;
                outacc[mt][j][2] += r2 * s;
            }
    }

    // ---- Write output: lanes with col<3 write component d=col ----
    if (col < 3) {
#pragma unroll
        for (int mt = 0; mt < 2; ++mt)
#pragma unroll
            for (int j = 0; j < 4; ++j) {
                const int q = qblk * 128 + w * 32 + mt * 16 + g * 4 + j;
                const size_t o = (((size_t)b * 7 + t) * 4096 + (size_t)q) * 3 + col;
                const float val = (col == 0) ? outacc[mt][j][0]
                                : (col == 1) ? outacc[mt][j][1]
                                             : outacc[mt][j][2];
                OUT[o] = val;
            }
    }
}

extern "C" void kernel_launch(void* const* d_in, const int* in_sizes, int n_in,
                              void* d_out, int out_size, void* d_ws, size_t ws_size,
                              hipStream_t stream) {
    const float* K  = (const float*)d_in[0];
    const float* V  = (const float*)d_in[1];
    const float* MK = (const float*)d_in[2];
    const float* MV = (const float*)d_in[3];
    float* OUT = (float*)d_out;
    dim3 grid(448);
    dim3 block(256);
    hipLaunchKernelGGL(kast_attn_kernel, grid, block, 0, stream, K, V, MK, MV, OUT);
}

// Round 3
// 135.126 us; speedup vs baseline: 1.5942x; 1.5942x over previous
//
#include <hip/hip_runtime.h>
#include <hip/hip_bf16.h>

typedef __attribute__((ext_vector_type(8))) _Float16 f16x8;
typedef __attribute__((ext_vector_type(2))) _Float16 f16x2;
typedef __attribute__((ext_vector_type(4))) float f32x4;

#define LOG2E 1.44269504088896340736f

__device__ __forceinline__ f16x2 pkrtz(float a, float b) {
    return __builtin_bit_cast(f16x2, __builtin_amdgcn_cvt_pkrtz(a, b));
}

// Grid: 896 blocks = 14 (b,t) * 64 q-blocks of 64. Block: 256 threads (4 waves).
// Each wave: 16 queries (one 16-row M-tile). K-tiles of 64 keys staged in LDS
// as fp16 (single-MFMA QK^T, v_cvt_pkrtz staging). Online softmax, base-2.
__global__ __launch_bounds__(256) void kast_attn_kernel(
    const float* __restrict__ K,   // (2,8,4096,64)
    const float* __restrict__ V,   // (2,8,4096,3)
    const float* __restrict__ MK,  // (2,7,1024,64)
    const float* __restrict__ MV,  // (2,7,1024,3)
    float* __restrict__ OUT)       // (2,7,4096,3)
{
    __shared__ alignas(16) _Float16 sK[64][64];
    __shared__ alignas(16) float sV[64][4];

    const int id = blockIdx.x;
    // XCD-chunked swizzle (896 % 8 == 0 -> bijective); groups same-(b,t)
    // blocks onto one XCD so its L2 holds that K-set.
    const int sw = (id & 7) * 112 + (id >> 3);
    const int bt = sw >> 6;       // 0..13
    const int qblk = sw & 63;     // 0..63
    const int b = bt / 7, t = bt % 7;

    const int tid = threadIdx.x;
    const int lane = tid & 63;
    const int w = tid >> 6;       // wave 0..3
    const int col = lane & 15;    // MFMA col / B-row selector
    const int g = lane >> 4;      // k-chunk group, also C-row group

    // ---- Load Q fragment (A operand), scaled by log2(e), fp16 ----
    const float* Qbase = K + (((size_t)b * 8 + (t + 1)) * 4096) * 64;
    f16x8 aq[2];
    {
        const int qrow = qblk * 64 + w * 16 + col;
        const float* qp = Qbase + (size_t)qrow * 64;
#pragma unroll
        for (int ch = 0; ch < 2; ++ch) {
            const int c0 = ch * 32 + g * 8;
            const f32x4 xa = *(const f32x4*)&qp[c0];
            const f32x4 xb = *(const f32x4*)&qp[c0 + 4];
            const f16x2 p0 = pkrtz(xa[0] * LOG2E, xa[1] * LOG2E);
            const f16x2 p1 = pkrtz(xa[2] * LOG2E, xa[3] * LOG2E);
            const f16x2 p2 = pkrtz(xb[0] * LOG2E, xb[1] * LOG2E);
            const f16x2 p3 = pkrtz(xb[2] * LOG2E, xb[3] * LOG2E);
            aq[ch] = (f16x8){p0[0], p0[1], p1[0], p1[1], p2[0], p2[1], p3[0], p3[1]};
        }
    }

    float outacc[4][3];
#pragma unroll
    for (int j = 0; j < 4; ++j) {
        outacc[j][0] = 0.f; outacc[j][1] = 0.f; outacc[j][2] = 0.f;
    }

    for (int phase = 0; phase < 2; ++phase) {
        const float* kp; const float* vp; int ntile; float wgt;
        if (phase == 0) {
            kp = K + (((size_t)b * 8 + t) * 4096) * 64;
            vp = V + (((size_t)b * 8 + t) * 4096) * 3;
            ntile = 64; wgt = 0.8f;
        } else {
            kp = MK + (((size_t)b * 7 + t) * 1024) * 64;
            vp = MV + (((size_t)b * 7 + t) * 1024) * 3;
            ntile = 16; wgt = 0.2f;
        }

        float mrun = -1e30f;
        float lsum[4] = {0.f, 0.f, 0.f, 0.f};
        float racc[4][3];
#pragma unroll
        for (int j = 0; j < 4; ++j) {
            racc[j][0] = 0.f; racc[j][1] = 0.f; racc[j][2] = 0.f;
        }

        for (int kt = 0; kt < ntile; ++kt) {
            // ---- Stage K tile (64x64 f32 -> fp16, XOR-swizzled) ----
            {
                const int r = tid >> 2;            // 0..63
                const int c0 = (tid & 3) * 16;     // 0,16,32,48
                const float* src = kp + ((size_t)(kt * 64 + r)) * 64 + c0;
                const f32x4* s4 = (const f32x4*)src;
                const int rs = (r & 7) << 3;
#pragma unroll
                for (int half = 0; half < 2; ++half) {
                    const f32x4 xa = s4[half * 2 + 0];
                    const f32x4 xb = s4[half * 2 + 1];
                    const f16x2 p0 = pkrtz(xa[0], xa[1]);
                    const f16x2 p1 = pkrtz(xa[2], xa[3]);
                    const f16x2 p2 = pkrtz(xb[0], xb[1]);
                    const f16x2 p3 = pkrtz(xb[2], xb[3]);
                    const f16x8 h = {p0[0], p0[1], p1[0], p1[1], p2[0], p2[1], p3[0], p3[1]};
                    *(f16x8*)&sK[r][(c0 + half * 8) ^ rs] = h;
                }
                if (tid < 192) {
                    const unsigned vr = (unsigned)tid / 3u;
                    const unsigned vd = (unsigned)tid - vr * 3u;
                    sV[vr][vd] = vp[(size_t)(kt * 64) * 3 + tid];
                }
            }
            __syncthreads();

            // ---- QK^T via fp16 MFMA ----
            f32x4 acc[4];
#pragma unroll
            for (int nt = 0; nt < 4; ++nt) acc[nt] = (f32x4){0.f, 0.f, 0.f, 0.f};

#pragma unroll
            for (int ch = 0; ch < 2; ++ch) {
                f16x8 bh[4];
#pragma unroll
                for (int nt = 0; nt < 4; ++nt) {
                    const int rr = nt * 16 + col;
                    const int cc = (ch * 32 + g * 8) ^ ((rr & 7) << 3);
                    bh[nt] = *(const f16x8*)&sK[rr][cc];
                }
#pragma unroll
                for (int nt = 0; nt < 4; ++nt)
                    acc[nt] = __builtin_amdgcn_mfma_f32_16x16x32_f16(aq[ch], bh[nt], acc[nt], 0, 0, 0);
            }

            // ---- Online softmax + PV accumulate ----
            {
                float tm = acc[0][0];
#pragma unroll
                for (int nt = 0; nt < 4; ++nt)
#pragma unroll
                    for (int j = 0; j < 4; ++j) tm = fmaxf(tm, acc[nt][j]);
                tm = fmaxf(tm, __shfl_xor(tm, 1, 16));
                tm = fmaxf(tm, __shfl_xor(tm, 2, 16));
                tm = fmaxf(tm, __shfl_xor(tm, 4, 16));
                tm = fmaxf(tm, __shfl_xor(tm, 8, 16));

                if (!__all(tm <= mrun)) {
                    const float mnew = fmaxf(mrun, tm);
                    const float scale = __builtin_amdgcn_exp2f(mrun - mnew);
#pragma unroll
                    for (int j = 0; j < 4; ++j) {
                        lsum[j] *= scale;
                        racc[j][0] *= scale;
                        racc[j][1] *= scale;
                        racc[j][2] *= scale;
                    }
                    mrun = mnew;
                }

#pragma unroll
                for (int nt = 0; nt < 4; ++nt) {
                    const int rr = nt * 16 + col;
                    const f32x4 vv = *(const f32x4*)&sV[rr][0];
#pragma unroll
                    for (int j = 0; j < 4; ++j) {
                        const float p = __builtin_amdgcn_exp2f(acc[nt][j] - mrun);
                        lsum[j] += p;
                        racc[j][0] += p * vv[0];
                        racc[j][1] += p * vv[1];
                        racc[j][2] += p * vv[2];
                    }
                }
            }
            __syncthreads();
        }

        // ---- Finalize phase: reduce across the 16 key-col lanes ----
#pragma unroll
        for (int j = 0; j < 4; ++j) {
            float ls = lsum[j];
            float r0 = racc[j][0];
            float r1 = racc[j][1];
            float r2 = racc[j][2];
#pragma unroll
            for (int off = 1; off < 16; off <<= 1) {
                ls += __shfl_xor(ls, off, 16);
                r0 += __shfl_xor(r0, off, 16);
                r1 += __shfl_xor(r1, off, 16);
                r2 += __shfl_xor(r2, off, 16);
            }
            const float s = wgt / ls;
            outacc[j][0] += r0 * s;
            outacc[j][1] += r1 * s;
            outacc[j][2] += r2 * s;
        }
    }

    // ---- Write output: lanes with col<3 write component d=col ----
    if (col < 3) {
#pragma unroll
        for (int j = 0; j < 4; ++j) {
            const int q = qblk * 64 + w * 16 + g * 4 + j;
            const size_t o = (((size_t)b * 7 + t) * 4096 + (size_t)q) * 3 + col;
            const float val = (col == 0) ? outacc[j][0]
                            : (col == 1) ? outacc[j][1]
                                         : outacc[j][2];
            OUT[o] = val;
        }
    }
}

extern "C" void kernel_launch(void* const* d_in, const int* in_sizes, int n_in,
                              void* d_out, int out_size, void* d_ws, size_t ws_size,
                              hipStream_t stream) {
    const float* K  = (const float*)d_in[0];
    const float* V  = (const float*)d_in[1];
    const float* MK = (const float*)d_in[2];
    const float* MV = (const float*)d_in[3];
    float* OUT = (float*)d_out;
    dim3 grid(896);
    dim3 block(256);
    hipLaunchKernelGGL(kast_attn_kernel, grid, block, 0, stream, K, V, MK, MV, OUT);
}

// Round 4
// 119.564 us; speedup vs baseline: 1.8018x; 1.1302x over previous
//
#include <hip/hip_runtime.h>

typedef __attribute__((ext_vector_type(2))) __fp16 h2;
typedef __attribute__((ext_vector_type(4))) __fp16 h4;
typedef __attribute__((ext_vector_type(8))) __fp16 h8;
typedef __attribute__((ext_vector_type(4))) float f32x4;

#define LOG2E 1.44269504088896340736f

__device__ __forceinline__ h2 pkrtz(float a, float b) {
    return __builtin_bit_cast(h2, __builtin_amdgcn_cvt_pkrtz(a, b));
}

// Grid: 896 = 14 (b,t) * 64 q-blocks of 64. Block: 256 threads (4 waves),
// each wave owns 16 queries. K-tiles of 64 keys, double-buffered LDS (fp16).
// QK^T swapped (A=K, B=Q) so P lands in the B-fragment layout of
// mfma_f32_16x16x16_f16; PV + lsum (ones row) run on the MFMA pipe.
__global__ __launch_bounds__(256) void kast_attn_kernel(
    const float* __restrict__ K,   // (2,8,4096,64)
    const float* __restrict__ V,   // (2,8,4096,3)
    const float* __restrict__ MK,  // (2,7,1024,64)
    const float* __restrict__ MV,  // (2,7,1024,3)
    float* __restrict__ OUT)       // (2,7,4096,3)
{
    __shared__ alignas(16) __fp16 sK[2][64][64];
    __shared__ alignas(16) __fp16 sVT[2][4][68];  // rows: d0,d1,d2,ones; padded

    const int id = blockIdx.x;
    // XCD-chunked swizzle (896 % 8 == 0 -> bijective)
    const int sw = (id & 7) * 112 + (id >> 3);
    const int bt = sw >> 6;       // 0..13
    const int qblk = sw & 63;     // 0..63
    const int b = bt / 7, t = bt % 7;

    const int tid = threadIdx.x;
    const int lane = tid & 63;
    const int w = tid >> 6;       // wave 0..3
    const int col = lane & 15;    // q within wave / A-frag row selector
    const int g = lane >> 4;      // k-chunk group

    // staging coords
    const int r = tid >> 2;            // 0..63 (key row)
    const int c0 = (tid & 3) * 16;     // 0,16,32,48
    const int rs = (r & 7) << 3;
    const unsigned vr = (unsigned)tid / 3u;
    const unsigned vd = (unsigned)tid - vr * 3u;

    // ones rows of V^T (static across all tiles/phases)
    if (tid < 128) sVT[tid >> 6][3][tid & 63] = (__fp16)1.0f;

    // ---- Q fragment (B operand), scaled by log2(e), fp16 ----
    const float* Qbase = K + (((size_t)b * 8 + (t + 1)) * 4096) * 64;
    h8 aq[2];
    {
        const int qrow = qblk * 64 + w * 16 + col;
        const float* qp = Qbase + (size_t)qrow * 64;
#pragma unroll
        for (int ch = 0; ch < 2; ++ch) {
            const int cc = ch * 32 + g * 8;
            const f32x4 xa = *(const f32x4*)&qp[cc];
            const f32x4 xb = *(const f32x4*)&qp[cc + 4];
            const h2 p0 = pkrtz(xa[0] * LOG2E, xa[1] * LOG2E);
            const h2 p1 = pkrtz(xa[2] * LOG2E, xa[3] * LOG2E);
            const h2 p2 = pkrtz(xb[0] * LOG2E, xb[1] * LOG2E);
            const h2 p3 = pkrtz(xb[2] * LOG2E, xb[3] * LOG2E);
            aq[ch] = (h8){p0[0], p0[1], p1[0], p1[1], p2[0], p2[1], p3[0], p3[1]};
        }
    }

    float outc0 = 0.f, outc1 = 0.f, outc2 = 0.f;

    for (int phase = 0; phase < 2; ++phase) {
        const float* kp; const float* vp; int ntile; float wgt;
        if (phase == 0) {
            kp = K + (((size_t)b * 8 + t) * 4096) * 64;
            vp = V + (((size_t)b * 8 + t) * 4096) * 3;
            ntile = 64; wgt = 0.8f;
        } else {
            kp = MK + (((size_t)b * 7 + t) * 1024) * 64;
            vp = MV + (((size_t)b * 7 + t) * 1024) * 3;
            ntile = 16; wgt = 0.2f;
        }

        // ---- prologue: stage tile 0 into buf 0 ----
        {
            const float* src = kp + ((size_t)r) * 64 + c0;
            const f32x4* s4 = (const f32x4*)src;
            const f32x4 ra = s4[0], rb = s4[1], rc = s4[2], rd = s4[3];
            const h2 q0 = pkrtz(ra[0], ra[1]), q1 = pkrtz(ra[2], ra[3]);
            const h2 q2 = pkrtz(rb[0], rb[1]), q3 = pkrtz(rb[2], rb[3]);
            const h2 q4 = pkrtz(rc[0], rc[1]), q5 = pkrtz(rc[2], rc[3]);
            const h2 q6 = pkrtz(rd[0], rd[1]), q7 = pkrtz(rd[2], rd[3]);
            *(h8*)&sK[0][r][c0 ^ rs] = (h8){q0[0], q0[1], q1[0], q1[1], q2[0], q2[1], q3[0], q3[1]};
            *(h8*)&sK[0][r][(c0 + 8) ^ rs] = (h8){q4[0], q4[1], q5[0], q5[1], q6[0], q6[1], q7[0], q7[1]};
            if (tid < 192) sVT[0][vd][vr] = (__fp16)vp[tid];
        }
        __syncthreads();

        float mrun = -1e30f;
        f32x4 O = (f32x4){0.f, 0.f, 0.f, 0.f};

        for (int kt = 0; kt < ntile; ++kt) {
            const int cur = kt & 1;
            const bool have = (kt + 1) < ntile;

            // ---- issue next tile's global loads early ----
            f32x4 ra, rb, rc, rd; float rv = 0.f;
            if (have) {
                const float* src = kp + ((size_t)(kt + 1) * 64 + r) * 64 + c0;
                const f32x4* s4 = (const f32x4*)src;
                ra = s4[0]; rb = s4[1]; rc = s4[2]; rd = s4[3];
                if (tid < 192) rv = vp[(size_t)(kt + 1) * 192 + tid];
            }

            // ---- QK^T (swapped: A=K frag, B=Q frag) ----
            f32x4 acc[4];
#pragma unroll
            for (int nt = 0; nt < 4; ++nt) acc[nt] = (f32x4){0.f, 0.f, 0.f, 0.f};
#pragma unroll
            for (int ch = 0; ch < 2; ++ch) {
                h8 bh[4];
#pragma unroll
                for (int nt = 0; nt < 4; ++nt) {
                    const int rr = nt * 16 + col;
                    const int cc = (ch * 32 + g * 8) ^ ((rr & 7) << 3);
                    bh[nt] = *(const h8*)&sK[cur][rr][cc];
                }
#pragma unroll
                for (int nt = 0; nt < 4; ++nt)
                    acc[nt] = __builtin_amdgcn_mfma_f32_16x16x32_f16(bh[nt], aq[ch], acc[nt], 0, 0, 0);
            }
            // lane holds S[key = nt*16 + 4g + j][q = col]

            // ---- online softmax (per-query max: 2 shuffles) ----
            {
                float tm = acc[0][0];
#pragma unroll
                for (int nt = 0; nt < 4; ++nt)
#pragma unroll
                    for (int j = 0; j < 4; ++j) tm = fmaxf(tm, acc[nt][j]);
                tm = fmaxf(tm, __shfl_xor(tm, 16));
                tm = fmaxf(tm, __shfl_xor(tm, 32));

                if (!__all(tm <= mrun)) {
                    const float mnew = fmaxf(mrun, tm);
                    const float sc = __builtin_amdgcn_exp2f(mrun - mnew);
                    O *= sc;
                    mrun = mnew;
                }
            }

            // ---- P = exp2(S - m) -> fp16, PV via mfma 16x16x16 ----
#pragma unroll
            for (int nt = 0; nt < 4; ++nt) {
                const float p0 = __builtin_amdgcn_exp2f(acc[nt][0] - mrun);
                const float p1 = __builtin_amdgcn_exp2f(acc[nt][1] - mrun);
                const float p2 = __builtin_amdgcn_exp2f(acc[nt][2] - mrun);
                const float p3 = __builtin_amdgcn_exp2f(acc[nt][3] - mrun);
                const h2 pa = pkrtz(p0, p1), pb = pkrtz(p2, p3);
                const h4 pf = (h4){pa[0], pa[1], pb[0], pb[1]};
                // V^T fragment: row d = col&3 (rows 4-15 duplicate -> unused D rows)
                const h4 vf = *(const h4*)&sVT[cur][col & 3][nt * 16 + 4 * g];
                O = __builtin_amdgcn_mfma_f32_16x16x16f16(vf, pf, O, 0, 0, 0);
            }

            // ---- write staged regs into the other buffer ----
            if (have) {
                const int nb = cur ^ 1;
                const h2 q0 = pkrtz(ra[0], ra[1]), q1 = pkrtz(ra[2], ra[3]);
                const h2 q2 = pkrtz(rb[0], rb[1]), q3 = pkrtz(rb[2], rb[3]);
                const h2 q4 = pkrtz(rc[0], rc[1]), q5 = pkrtz(rc[2], rc[3]);
                const h2 q6 = pkrtz(rd[0], rd[1]), q7 = pkrtz(rd[2], rd[3]);
                *(h8*)&sK[nb][r][c0 ^ rs] = (h8){q0[0], q0[1], q1[0], q1[1], q2[0], q2[1], q3[0], q3[1]};
                *(h8*)&sK[nb][r][(c0 + 8) ^ rs] = (h8){q4[0], q4[1], q5[0], q5[1], q6[0], q6[1], q7[0], q7[1]};
                if (tid < 192) sVT[nb][vd][vr] = (__fp16)rv;
            }
            __syncthreads();
        }

        // ---- phase epilogue: O = [d0, d1, d2, lsum] on lanes g==0 ----
        const float inv = wgt / O[3];
        outc0 += O[0] * inv;
        outc1 += O[1] * inv;
        outc2 += O[2] * inv;
    }

    // ---- write output (lanes 0..15 hold q = col) ----
    if (g == 0) {
        const int q = qblk * 64 + w * 16 + col;
        float* op = OUT + (((size_t)b * 7 + t) * 4096 + (size_t)q) * 3;
        op[0] = outc0; op[1] = outc1; op[2] = outc2;
    }
}

extern "C" void kernel_launch(void* const* d_in, const int* in_sizes, int n_in,
                              void* d_out, int out_size, void* d_ws, size_t ws_size,
                              hipStream_t stream) {
    const float* K  = (const float*)d_in[0];
    const float* V  = (const float*)d_in[1];
    const float* MK = (const float*)d_in[2];
    const float* MV = (const float*)d_in[3];
    float* OUT = (float*)d_out;
    dim3 grid(896);
    dim3 block(256);
    hipLaunchKernelGGL(kast_attn_kernel, grid, block, 0, stream, K, V, MK, MV, OUT);
}

// Round 6
// 119.014 us; speedup vs baseline: 1.8101x; 1.0046x over previous
//
#include <hip/hip_runtime.h>

typedef __attribute__((ext_vector_type(2))) __fp16 h2;
typedef __attribute__((ext_vector_type(4))) __fp16 h4;
typedef __attribute__((ext_vector_type(8))) __fp16 h8;
typedef __attribute__((ext_vector_type(4))) float f32x4;

#define LOG2E 1.44269504088896340736f

// ws layout (bytes)
#define WS_K    0ull            // 14*64 tiles * 8192 B
#define WS_MK   7340032ull      // 14*16 tiles * 8192 B
#define WS_VT   9175040ull      // 14*64 tiles * 512 B
#define WS_MVT  9633792ull      // 14*16 tiles * 512 B
#define WS_NEED 9748480ull

__device__ __forceinline__ h2 pkrtz(float a, float b) {
    return __builtin_bit_cast(h2, __builtin_amdgcn_cvt_pkrtz(a, b));
}

__device__ __forceinline__ void gll16(const void* g, void* l) {
    __builtin_amdgcn_global_load_lds(
        (const __attribute__((address_space(1))) unsigned int*)g,
        (__attribute__((address_space(3))) unsigned int*)l, 16, 0, 0);
}

// ---------------- Precompute: f32 -> fp16 tiles, swizzle baked in ----------------
// Seg0: K granules  (14*64*64*8): 16B h8 granule c of row r stored at pos c^(r&7).
// Seg1: MK granules (14*16*64*8)
// Seg2: VT granules (14*64*4*16): 8B h4; row d (d3=ones), logical granule c
//       stored at pos 4*((c>>2)^d)+(c&3)  -> conflict-free PV reads.
// Seg3: MVT granules (14*16*4*16). Total ids 645120 = 2520*256.
__global__ __launch_bounds__(256) void kast_pre_kernel(
    const float* __restrict__ K, const float* __restrict__ V,
    const float* __restrict__ MK, const float* __restrict__ MV,
    char* __restrict__ ws)
{
    const int id = blockIdx.x * 256 + threadIdx.x;
    if (id < 573440) {
        const bool ismk = id >= 458752;
        const int lid = ismk ? id - 458752 : id;
        const int c = lid & 7;
        const int r = (lid >> 3) & 63;
        int kt, s;
        if (ismk) { kt = (lid >> 9) & 15; s = lid >> 13; }
        else      { kt = (lid >> 9) & 63; s = lid >> 15; }
        const int b = s / 7, t = s - b * 7;
        const float* src = ismk
            ? MK + (((size_t)(b * 7 + t) * 1024 + kt * 64 + r) * 64 + c * 8)
            : K  + (((size_t)(b * 8 + t) * 4096 + kt * 64 + r) * 64 + c * 8);
        const f32x4 xa = *(const f32x4*)src;
        const f32x4 xb = *(const f32x4*)(src + 4);
        const h2 q0 = pkrtz(xa[0], xa[1]), q1 = pkrtz(xa[2], xa[3]);
        const h2 q2 = pkrtz(xb[0], xb[1]), q3 = pkrtz(xb[2], xb[3]);
        const h8 out = {q0[0], q0[1], q1[0], q1[1], q2[0], q2[1], q3[0], q3[1]};
        __fp16* dst = (__fp16*)(ws + (ismk ? WS_MK : WS_K))
                    + (size_t)(ismk ? (s * 16 + kt) : (s * 64 + kt)) * 4096
                    + r * 64 + ((c ^ (r & 7)) * 8);
        *(h8*)dst = out;
    } else {
        const int vid = id - 573440;
        const bool ismv = vid >= 57344;
        const int lid = ismv ? vid - 57344 : vid;
        const int c = lid & 15;
        const int d = (lid >> 4) & 3;
        int kt, s;
        if (ismv) { kt = (lid >> 6) & 15; s = lid >> 10; }
        else      { kt = (lid >> 6) & 63; s = lid >> 12; }
        const int b = s / 7, t = s - b * 7;
        const float* src = ismv
            ? MV + (((size_t)(b * 7 + t) * 1024 + kt * 64 + c * 4) * 3)
            : V  + (((size_t)(b * 8 + t) * 4096 + kt * 64 + c * 4) * 3);
        float f0, f1, f2, f3;
        if (d == 3) { f0 = f1 = f2 = f3 = 1.0f; }
        else { f0 = src[d]; f1 = src[3 + d]; f2 = src[6 + d]; f3 = src[9 + d]; }
        const h2 pa = pkrtz(f0, f1), pb = pkrtz(f2, f3);
        const h4 out4 = {pa[0], pa[1], pb[0], pb[1]};
        __fp16* dst = (__fp16*)(ws + (ismv ? WS_MVT : WS_VT))
                    + (size_t)(ismv ? (s * 16 + kt) : (s * 64 + kt)) * 256
                    + d * 64 + (4 * ((c >> 2) ^ d) + (c & 3)) * 4;
        *(h4*)dst = out4;
    }
}

// ---------------- Main: gload_lds K-staging, 2-buffer, __syncthreads drains ----------------
__global__ __launch_bounds__(256) void kast_attn_kernel(
    const float* __restrict__ K,   // (2,8,4096,64) for Q
    const char* __restrict__ ws,
    float* __restrict__ OUT)       // (2,7,4096,3)
{
    __shared__ alignas(16) __fp16 sK2[2][64][64];
    __shared__ alignas(16) __fp16 sVT2[2][4][64];

    const int id = blockIdx.x;
    const int sw = (id & 7) * 112 + (id >> 3);   // XCD-chunked, bijective (896%8==0)
    const int bt = sw >> 6;
    const int qblk = sw & 63;
    const int b = bt / 7, t = bt - b * 7;

    const int tid = threadIdx.x;
    const int lane = tid & 63;
    const int w = tid >> 6;
    const int col = lane & 15;
    const int g = lane >> 4;
    const int cs = col & 7;      // K-read swizzle key (row&7 == col&7)
    const int d3 = col & 3;      // V^T row

    // ---- Q fragment (B operand), scaled by log2(e) ----
    const float* qp = K + (((size_t)b * 8 + (t + 1)) * 4096 + (size_t)(qblk * 64 + w * 16 + col)) * 64;
    h8 aq[2];
#pragma unroll
    for (int ch = 0; ch < 2; ++ch) {
        const int cc = ch * 32 + g * 8;
        const f32x4 xa = *(const f32x4*)&qp[cc];
        const f32x4 xb = *(const f32x4*)&qp[cc + 4];
        const h2 p0 = pkrtz(xa[0] * LOG2E, xa[1] * LOG2E);
        const h2 p1 = pkrtz(xa[2] * LOG2E, xa[3] * LOG2E);
        const h2 p2 = pkrtz(xb[0] * LOG2E, xb[1] * LOG2E);
        const h2 p3 = pkrtz(xb[2] * LOG2E, xb[3] * LOG2E);
        aq[ch] = (h8){p0[0], p0[1], p1[0], p1[1], p2[0], p2[1], p3[0], p3[1]};
    }

    float outc0 = 0.f, outc1 = 0.f, outc2 = 0.f;

    auto stageK = [&](const char* kb, int tkt, int buf) {
        const char* ksrc = kb + (size_t)tkt * 8192 + w * 2048 + lane * 16;
        char* kdst = ((char*)&sK2[buf][0][0]) + w * 2048 + lane * 16;
        gll16(ksrc, kdst);
        gll16(ksrc + 1024, kdst + 1024);
    };

    for (int phase = 0; phase < 2; ++phase) {
        const char* kbase; const char* vbase; int ntile; float wgt;
        if (phase == 0) {
            kbase = ws + WS_K  + (size_t)bt * 64 * 8192;
            vbase = ws + WS_VT + (size_t)bt * 64 * 512;
            ntile = 64; wgt = 0.8f;
        } else {
            kbase = ws + WS_MK  + (size_t)bt * 16 * 8192;
            vbase = ws + WS_MVT + (size_t)bt * 16 * 512;
            ntile = 16; wgt = 0.2f;
        }

        // prologue: tile 0 -> buf 0
        stageK(kbase, 0, 0);
        if (tid < 32)
            ((f32x4*)&sVT2[0][0][0])[tid] = ((const f32x4*)vbase)[tid];
        __syncthreads();

        float mrun = -1e30f;
        f32x4 O = (f32x4){0.f, 0.f, 0.f, 0.f};

        for (int kt = 0; kt < ntile; ++kt) {
            const int cur = kt & 1;
            const int nb = cur ^ 1;

            // issue next tile's staging early; end-of-iter __syncthreads drains it
            if (kt + 1 < ntile) {
                stageK(kbase, kt + 1, nb);
                if (tid < 32)
                    ((f32x4*)&sVT2[nb][0][0])[tid] =
                        ((const f32x4*)(vbase + (size_t)(kt + 1) * 512))[tid];
            }

            // ---- QK^T (swapped: A=K frag, B=Q frag) ----
            f32x4 acc[4];
#pragma unroll
            for (int nt = 0; nt < 4; ++nt) acc[nt] = (f32x4){0.f, 0.f, 0.f, 0.f};
            __builtin_amdgcn_s_setprio(1);
#pragma unroll
            for (int ch = 0; ch < 2; ++ch) {
                h8 bh[4];
#pragma unroll
                for (int nt = 0; nt < 4; ++nt)
                    bh[nt] = *(const h8*)&sK2[cur][nt * 16 + col][((ch * 4 + g) ^ cs) * 8];
#pragma unroll
                for (int nt = 0; nt < 4; ++nt)
                    acc[nt] = __builtin_amdgcn_mfma_f32_16x16x32_f16(bh[nt], aq[ch], acc[nt], 0, 0, 0);
            }
            __builtin_amdgcn_s_setprio(0);
            // lane holds S[key = nt*16 + 4g + j][q = col]

            // ---- online softmax (per-query max: 2 shuffles) ----
            {
                float tm = acc[0][0];
#pragma unroll
                for (int nt = 0; nt < 4; ++nt)
#pragma unroll
                    for (int j = 0; j < 4; ++j) tm = fmaxf(tm, acc[nt][j]);
                tm = fmaxf(tm, __shfl_xor(tm, 16));
                tm = fmaxf(tm, __shfl_xor(tm, 32));
                if (!__all(tm <= mrun)) {
                    const float mnew = fmaxf(mrun, tm);
                    const float sc = __builtin_amdgcn_exp2f(mrun - mnew);
                    O *= sc;
                    mrun = mnew;
                }
            }

            // ---- P = exp2(S-m) -> fp16, PV + lsum on MFMA pipe ----
            const char* vtb = (const char*)&sVT2[cur][0][0] + d3 * 128;
#pragma unroll
            for (int nt = 0; nt < 4; ++nt) {
                const float p0 = __builtin_amdgcn_exp2f(acc[nt][0] - mrun);
                const float p1 = __builtin_amdgcn_exp2f(acc[nt][1] - mrun);
                const float p2 = __builtin_amdgcn_exp2f(acc[nt][2] - mrun);
                const float p3 = __builtin_amdgcn_exp2f(acc[nt][3] - mrun);
                const h2 pa = pkrtz(p0, p1), pb = pkrtz(p2, p3);
                const h4 pf = (h4){pa[0], pa[1], pb[0], pb[1]};
                const h4 vf = *(const h4*)(vtb + (4 * (nt ^ d3) + g) * 8);
                O = __builtin_amdgcn_mfma_f32_16x16x16f16(vf, pf, O, 0, 0, 0);
            }

            __syncthreads();  // full drain: staged tile kt+1 landed; safe buffer swap
        }

        const float inv = wgt / O[3];
        outc0 += O[0] * inv;
        outc1 += O[1] * inv;
        outc2 += O[2] * inv;
    }

    if (g == 0) {
        const int q = qblk * 64 + w * 16 + col;
        float* op = OUT + (((size_t)b * 7 + t) * 4096 + (size_t)q) * 3;
        op[0] = outc0; op[1] = outc1; op[2] = outc2;
    }
}

// ---------------- Fallback (round-4 kernel, known-good) if ws too small ----------------
__global__ __launch_bounds__(256) void kast_attn_fb(
    const float* __restrict__ K, const float* __restrict__ V,
    const float* __restrict__ MK, const float* __restrict__ MV,
    float* __restrict__ OUT)
{
    __shared__ alignas(16) __fp16 sK[2][64][64];
    __shared__ alignas(16) __fp16 sVT[2][4][68];

    const int id = blockIdx.x;
    const int sw = (id & 7) * 112 + (id >> 3);
    const int bt = sw >> 6;
    const int qblk = sw & 63;
    const int b = bt / 7, t = bt % 7;

    const int tid = threadIdx.x;
    const int lane = tid & 63;
    const int w = tid >> 6;
    const int col = lane & 15;
    const int g = lane >> 4;

    const int r = tid >> 2;
    const int c0 = (tid & 3) * 16;
    const int rs = (r & 7) << 3;
    const unsigned vr = (unsigned)tid / 3u;
    const unsigned vd = (unsigned)tid - vr * 3u;

    if (tid < 128) sVT[tid >> 6][3][tid & 63] = (__fp16)1.0f;

    const float* Qbase = K + (((size_t)b * 8 + (t + 1)) * 4096) * 64;
    h8 aq[2];
    {
        const int qrow = qblk * 64 + w * 16 + col;
        const float* qp = Qbase + (size_t)qrow * 64;
#pragma unroll
        for (int ch = 0; ch < 2; ++ch) {
            const int cc = ch * 32 + g * 8;
            const f32x4 xa = *(const f32x4*)&qp[cc];
            const f32x4 xb = *(const f32x4*)&qp[cc + 4];
            const h2 p0 = pkrtz(xa[0] * LOG2E, xa[1] * LOG2E);
            const h2 p1 = pkrtz(xa[2] * LOG2E, xa[3] * LOG2E);
            const h2 p2 = pkrtz(xb[0] * LOG2E, xb[1] * LOG2E);
            const h2 p3 = pkrtz(xb[2] * LOG2E, xb[3] * LOG2E);
            aq[ch] = (h8){p0[0], p0[1], p1[0], p1[1], p2[0], p2[1], p3[0], p3[1]};
        }
    }

    float outc0 = 0.f, outc1 = 0.f, outc2 = 0.f;

    for (int phase = 0; phase < 2; ++phase) {
        const float* kp; const float* vp; int ntile; float wgt;
        if (phase == 0) {
            kp = K + (((size_t)b * 8 + t) * 4096) * 64;
            vp = V + (((size_t)b * 8 + t) * 4096) * 3;
            ntile = 64; wgt = 0.8f;
        } else {
            kp = MK + (((size_t)b * 7 + t) * 1024) * 64;
            vp = MV + (((size_t)b * 7 + t) * 1024) * 3;
            ntile = 16; wgt = 0.2f;
        }
        {
            const float* src = kp + ((size_t)r) * 64 + c0;
            const f32x4* s4 = (const f32x4*)src;
            const f32x4 ra = s4[0], rb = s4[1], rc = s4[2], rd = s4[3];
            const h2 q0 = pkrtz(ra[0], ra[1]), q1 = pkrtz(ra[2], ra[3]);
            const h2 q2 = pkrtz(rb[0], rb[1]), q3 = pkrtz(rb[2], rb[3]);
            const h2 q4 = pkrtz(rc[0], rc[1]), q5 = pkrtz(rc[2], rc[3]);
            const h2 q6 = pkrtz(rd[0], rd[1]), q7 = pkrtz(rd[2], rd[3]);
            *(h8*)&sK[0][r][c0 ^ rs] = (h8){q0[0], q0[1], q1[0], q1[1], q2[0], q2[1], q3[0], q3[1]};
            *(h8*)&sK[0][r][(c0 + 8) ^ rs] = (h8){q4[0], q4[1], q5[0], q5[1], q6[0], q6[1], q7[0], q7[1]};
            if (tid < 192) sVT[0][vd][vr] = (__fp16)vp[tid];
        }
        __syncthreads();

        float mrun = -1e30f;
        f32x4 O = (f32x4){0.f, 0.f, 0.f, 0.f};

        for (int kt = 0; kt < ntile; ++kt) {
            const int cur = kt & 1;
            const bool have = (kt + 1) < ntile;
            f32x4 ra, rb, rc, rd; float rv = 0.f;
            if (have) {
                const float* src = kp + ((size_t)(kt + 1) * 64 + r) * 64 + c0;
                const f32x4* s4 = (const f32x4*)src;
                ra = s4[0]; rb = s4[1]; rc = s4[2]; rd = s4[3];
                if (tid < 192) rv = vp[(size_t)(kt + 1) * 192 + tid];
            }
            f32x4 acc[4];
#pragma unroll
            for (int nt = 0; nt < 4; ++nt) acc[nt] = (f32x4){0.f, 0.f, 0.f, 0.f};
#pragma unroll
            for (int ch = 0; ch < 2; ++ch) {
                h8 bh[4];
#pragma unroll
                for (int nt = 0; nt < 4; ++nt) {
                    const int rr = nt * 16 + col;
                    const int cc = (ch * 32 + g * 8) ^ ((rr & 7) << 3);
                    bh[nt] = *(const h8*)&sK[cur][rr][cc];
                }
#pragma unroll
                for (int nt = 0; nt < 4; ++nt)
                    acc[nt] = __builtin_amdgcn_mfma_f32_16x16x32_f16(bh[nt], aq[ch], acc[nt], 0, 0, 0);
            }
            {
                float tm = acc[0][0];
#pragma unroll
                for (int nt = 0; nt < 4; ++nt)
#pragma unroll
                    for (int j = 0; j < 4; ++j) tm = fmaxf(tm, acc[nt][j]);
                tm = fmaxf(tm, __shfl_xor(tm, 16));
                tm = fmaxf(tm, __shfl_xor(tm, 32));
                if (!__all(tm <= mrun)) {
                    const float mnew = fmaxf(mrun, tm);
                    const float sc = __builtin_amdgcn_exp2f(mrun - mnew);
                    O *= sc;
                    mrun = mnew;
                }
            }
#pragma unroll
            for (int nt = 0; nt < 4; ++nt) {
                const float p0 = __builtin_amdgcn_exp2f(acc[nt][0] - mrun);
                const float p1 = __builtin_amdgcn_exp2f(acc[nt][1] - mrun);
                const float p2 = __builtin_amdgcn_exp2f(acc[nt][2] - mrun);
                const float p3 = __builtin_amdgcn_exp2f(acc[nt][3] - mrun);
                const h2 pa = pkrtz(p0, p1), pb = pkrtz(p2, p3);
                const h4 pf = (h4){pa[0], pa[1], pb[0], pb[1]};
                const h4 vf = *(const h4*)&sVT[cur][col & 3][nt * 16 + 4 * g];
                O = __builtin_amdgcn_mfma_f32_16x16x16f16(vf, pf, O, 0, 0, 0);
            }
            if (have) {
                const int nb = cur ^ 1;
                const h2 q0 = pkrtz(ra[0], ra[1]), q1 = pkrtz(ra[2], ra[3]);
                const h2 q2 = pkrtz(rb[0], rb[1]), q3 = pkrtz(rb[2], rb[3]);
                const h2 q4 = pkrtz(rc[0], rc[1]), q5 = pkrtz(rc[2], rc[3]);
                const h2 q6 = pkrtz(rd[0], rd[1]), q7 = pkrtz(rd[2], rd[3]);
                *(h8*)&sK[nb][r][c0 ^ rs] = (h8){q0[0], q0[1], q1[0], q1[1], q2[0], q2[1], q3[0], q3[1]};
                *(h8*)&sK[nb][r][(c0 + 8) ^ rs] = (h8){q4[0], q4[1], q5[0], q5[1], q6[0], q6[1], q7[0], q7[1]};
                if (tid < 192) sVT[nb][vd][vr] = (__fp16)rv;
            }
            __syncthreads();
        }
        const float inv = wgt / O[3];
        outc0 += O[0] * inv;
        outc1 += O[1] * inv;
        outc2 += O[2] * inv;
    }

    if (g == 0) {
        const int q = qblk * 64 + w * 16 + col;
        float* op = OUT + (((size_t)b * 7 + t) * 4096 + (size_t)q) * 3;
        op[0] = outc0; op[1] = outc1; op[2] = outc2;
    }
}

extern "C" void kernel_launch(void* const* d_in, const int* in_sizes, int n_in,
                              void* d_out, int out_size, void* d_ws, size_t ws_size,
                              hipStream_t stream) {
    const float* K  = (const float*)d_in[0];
    const float* V  = (const float*)d_in[1];
    const float* MK = (const float*)d_in[2];
    const float* MV = (const float*)d_in[3];
    float* OUT = (float*)d_out;
    if (ws_size >= WS_NEED) {
        hipLaunchKernelGGL(kast_pre_kernel, dim3(2520), dim3(256), 0, stream,
                           K, V, MK, MV, (char*)d_ws);
        hipLaunchKernelGGL(kast_attn_kernel, dim3(896), dim3(256), 0, stream,
                           K, (const char*)d_ws, OUT);
    } else {
        hipLaunchKernelGGL(kast_attn_fb, dim3(896), dim3(256), 0, stream,
                           K, V, MK, MV, OUT);
    }
}

// Round 7
// 96.873 us; speedup vs baseline: 2.2238x; 1.2286x over previous
//
#include <hip/hip_runtime.h>

typedef __attribute__((ext_vector_type(2))) __fp16 h2;
typedef __attribute__((ext_vector_type(4))) __fp16 h4;
typedef __attribute__((ext_vector_type(8))) __fp16 h8;
typedef __attribute__((ext_vector_type(4))) float f32x4;

#define LOG2E 1.44269504088896340736f

// ws layout (bytes)
#define WS_K    0ull            // 14*64 tiles * 8192 B
#define WS_MK   7340032ull      // 14*16 tiles * 8192 B
#define WS_VT   9175040ull      // 14*64 tiles * 512 B
#define WS_MVT  9633792ull      // 14*16 tiles * 512 B
#define WS_NEED 9748480ull

__device__ __forceinline__ h2 pkrtz(float a, float b) {
    return __builtin_bit_cast(h2, __builtin_amdgcn_cvt_pkrtz(a, b));
}

__device__ __forceinline__ void gll16(const void* g, void* l) {
    __builtin_amdgcn_global_load_lds(
        (const __attribute__((address_space(1))) unsigned int*)g,
        (__attribute__((address_space(3))) unsigned int*)l, 16, 0, 0);
}

// ---------------- Precompute: f32 -> fp16 tiles, swizzle baked in ----------------
// Seg0: K granules  (14*64*64*8): 16B h8 granule c of row r stored at pos c^(r&7).
// Seg1: MK granules (14*16*64*8)
// Seg2: VT granules (14*64*4*16): 8B h4; row d (d3=ones), logical granule c
//       stored at pos 4*((c>>2)^d)+(c&3)  -> conflict-free PV reads.
// Seg3: MVT granules (14*16*4*16). Total ids 645120 = 2520*256.
__global__ __launch_bounds__(256) void kast_pre_kernel(
    const float* __restrict__ K, const float* __restrict__ V,
    const float* __restrict__ MK, const float* __restrict__ MV,
    char* __restrict__ ws)
{
    const int id = blockIdx.x * 256 + threadIdx.x;
    if (id < 573440) {
        const bool ismk = id >= 458752;
        const int lid = ismk ? id - 458752 : id;
        const int c = lid & 7;
        const int r = (lid >> 3) & 63;
        int kt, s;
        if (ismk) { kt = (lid >> 9) & 15; s = lid >> 13; }
        else      { kt = (lid >> 9) & 63; s = lid >> 15; }
        const int b = s / 7, t = s - b * 7;
        const float* src = ismk
            ? MK + (((size_t)(b * 7 + t) * 1024 + kt * 64 + r) * 64 + c * 8)
            : K  + (((size_t)(b * 8 + t) * 4096 + kt * 64 + r) * 64 + c * 8);
        const f32x4 xa = *(const f32x4*)src;
        const f32x4 xb = *(const f32x4*)(src + 4);
        const h2 q0 = pkrtz(xa[0], xa[1]), q1 = pkrtz(xa[2], xa[3]);
        const h2 q2 = pkrtz(xb[0], xb[1]), q3 = pkrtz(xb[2], xb[3]);
        const h8 out = {q0[0], q0[1], q1[0], q1[1], q2[0], q2[1], q3[0], q3[1]};
        __fp16* dst = (__fp16*)(ws + (ismk ? WS_MK : WS_K))
                    + (size_t)(ismk ? (s * 16 + kt) : (s * 64 + kt)) * 4096
                    + r * 64 + ((c ^ (r & 7)) * 8);
        *(h8*)dst = out;
    } else {
        const int vid = id - 573440;
        const bool ismv = vid >= 57344;
        const int lid = ismv ? vid - 57344 : vid;
        const int c = lid & 15;
        const int d = (lid >> 4) & 3;
        int kt, s;
        if (ismv) { kt = (lid >> 6) & 15; s = lid >> 10; }
        else      { kt = (lid >> 6) & 63; s = lid >> 12; }
        const int b = s / 7, t = s - b * 7;
        const float* src = ismv
            ? MV + (((size_t)(b * 7 + t) * 1024 + kt * 64 + c * 4) * 3)
            : V  + (((size_t)(b * 8 + t) * 4096 + kt * 64 + c * 4) * 3);
        float f0, f1, f2, f3;
        if (d == 3) { f0 = f1 = f2 = f3 = 1.0f; }
        else { f0 = src[d]; f1 = src[3 + d]; f2 = src[6 + d]; f3 = src[9 + d]; }
        const h2 pa = pkrtz(f0, f1), pb = pkrtz(f2, f3);
        const h4 out4 = {pa[0], pa[1], pb[0], pb[1]};
        __fp16* dst = (__fp16*)(ws + (ismv ? WS_MVT : WS_VT))
                    + (size_t)(ismv ? (s * 16 + kt) : (s * 64 + kt)) * 256
                    + d * 64 + (4 * ((c >> 2) ^ d) + (c & 3)) * 4;
        *(h4*)dst = out4;
    }
}

// ---------------- Main: 512 threads = 2 key-halves x 4 waves, flash merge ----------------
__global__ __launch_bounds__(512) void kast_attn_kernel(
    const float* __restrict__ K,   // (2,8,4096,64) for Q
    const char* __restrict__ ws,
    float* __restrict__ OUT)       // (2,7,4096,3)
{
    __shared__ alignas(16) __fp16 sK2[2][2][64][64];   // [half][buf]
    __shared__ alignas(16) __fp16 sVT2[2][2][4][64];
    __shared__ float mrg[8][16][10];                   // [wave][q][{m,O0..O3}x2phases]

    const int id = blockIdx.x;
    const int sw = (id & 7) * 112 + (id >> 3);   // XCD-chunked, bijective (896%8==0)
    const int bt = sw >> 6;
    const int qblk = sw & 63;
    const int b = bt / 7, t = bt - b * 7;

    const int tid = threadIdx.x;
    const int lane = tid & 63;
    const int w = tid >> 6;      // wave 0..7
    const int h = w >> 2;        // key-half 0/1
    const int wl = w & 3;        // wave within half
    const int col = lane & 15;   // q within wave / A-frag row selector
    const int g = lane >> 4;     // k-chunk group
    const int cs = col & 7;      // K-read swizzle key
    const int d3 = col & 3;      // V^T row

    // ---- Q fragment (B operand), scaled by log2(e) ----
    const float* qp = K + (((size_t)b * 8 + (t + 1)) * 4096 + (size_t)(qblk * 64 + wl * 16 + col)) * 64;
    h8 aq[2];
#pragma unroll
    for (int ch = 0; ch < 2; ++ch) {
        const int cc = ch * 32 + g * 8;
        const f32x4 xa = *(const f32x4*)&qp[cc];
        const f32x4 xb = *(const f32x4*)&qp[cc + 4];
        const h2 p0 = pkrtz(xa[0] * LOG2E, xa[1] * LOG2E);
        const h2 p1 = pkrtz(xa[2] * LOG2E, xa[3] * LOG2E);
        const h2 p2 = pkrtz(xb[0] * LOG2E, xb[1] * LOG2E);
        const h2 p3 = pkrtz(xb[2] * LOG2E, xb[3] * LOG2E);
        aq[ch] = (h8){p0[0], p0[1], p1[0], p1[1], p2[0], p2[1], p3[0], p3[1]};
    }

    auto stage = [&](const char* kb, const char* vb, int tkt, int buf) {
        const char* ksrc = kb + (size_t)tkt * 8192 + wl * 2048 + lane * 16;
        char* kdst = ((char*)&sK2[h][buf][0][0]) + wl * 2048 + lane * 16;
        gll16(ksrc, kdst);
        gll16(ksrc + 1024, kdst + 1024);
        if (wl == 0 && lane < 32)
            ((f32x4*)&sVT2[h][buf][0][0])[lane] =
                ((const f32x4*)(vb + (size_t)tkt * 512))[lane];
    };

#pragma unroll
    for (int phase = 0; phase < 2; ++phase) {
        const char* kbase; const char* vbase; int ntile;
        if (phase == 0) {
            ntile = 32;   // per half
            kbase = ws + WS_K  + ((size_t)bt * 64 + h * 32) * 8192;
            vbase = ws + WS_VT + ((size_t)bt * 64 + h * 32) * 512;
        } else {
            ntile = 8;
            kbase = ws + WS_MK  + ((size_t)bt * 16 + h * 8) * 8192;
            vbase = ws + WS_MVT + ((size_t)bt * 16 + h * 8) * 512;
        }

        // prologue: tile 0 -> buf 0
        stage(kbase, vbase, 0, 0);
        __syncthreads();

        float mrun = -1e30f;
        f32x4 O = (f32x4){0.f, 0.f, 0.f, 0.f};

        for (int kt = 0; kt < ntile; ++kt) {
            const int cur = kt & 1;
            const int nb = cur ^ 1;

            // issue next tile's staging early; end-of-iter __syncthreads drains it
            if (kt + 1 < ntile) stage(kbase, vbase, kt + 1, nb);

            // ---- QK^T (swapped: A=K frag, B=Q frag) ----
            f32x4 acc[4];
#pragma unroll
            for (int nt = 0; nt < 4; ++nt) acc[nt] = (f32x4){0.f, 0.f, 0.f, 0.f};
            __builtin_amdgcn_s_setprio(1);
#pragma unroll
            for (int ch = 0; ch < 2; ++ch) {
                h8 bh[4];
#pragma unroll
                for (int nt = 0; nt < 4; ++nt)
                    bh[nt] = *(const h8*)&sK2[h][cur][nt * 16 + col][((ch * 4 + g) ^ cs) * 8];
#pragma unroll
                for (int nt = 0; nt < 4; ++nt)
                    acc[nt] = __builtin_amdgcn_mfma_f32_16x16x32_f16(bh[nt], aq[ch], acc[nt], 0, 0, 0);
            }
            __builtin_amdgcn_s_setprio(0);
            // lane holds S[key = nt*16 + 4g + j][q = col]

            // ---- online softmax (per-query max: 2 shuffles) ----
            {
                float tm = acc[0][0];
#pragma unroll
                for (int nt = 0; nt < 4; ++nt)
#pragma unroll
                    for (int j = 0; j < 4; ++j) tm = fmaxf(tm, acc[nt][j]);
                tm = fmaxf(tm, __shfl_xor(tm, 16));
                tm = fmaxf(tm, __shfl_xor(tm, 32));
                if (!__all(tm <= mrun)) {
                    const float mnew = fmaxf(mrun, tm);
                    const float sc = __builtin_amdgcn_exp2f(mrun - mnew);
                    O *= sc;
                    mrun = mnew;
                }
            }

            // ---- P = exp2(S-m) -> fp16, PV + lsum on MFMA pipe ----
            const char* vtb = (const char*)&sVT2[h][cur][0][0] + d3 * 128;
#pragma unroll
            for (int nt = 0; nt < 4; ++nt) {
                const float p0 = __builtin_amdgcn_exp2f(acc[nt][0] - mrun);
                const float p1 = __builtin_amdgcn_exp2f(acc[nt][1] - mrun);
                const float p2 = __builtin_amdgcn_exp2f(acc[nt][2] - mrun);
                const float p3 = __builtin_amdgcn_exp2f(acc[nt][3] - mrun);
                const h2 pa = pkrtz(p0, p1), pb = pkrtz(p2, p3);
                const h4 pf = (h4){pa[0], pa[1], pb[0], pb[1]};
                const h4 vf = *(const h4*)(vtb + (4 * (nt ^ d3) + g) * 8);
                O = __builtin_amdgcn_mfma_f32_16x16x16f16(vf, pf, O, 0, 0, 0);
            }

            __syncthreads();  // drains staged tile kt+1; safe buffer swap
        }

        // ---- phase partials to LDS (own slice; read after final sync) ----
        if (g == 0) {
            float* m5 = &mrg[w][col][phase * 5];
            m5[0] = mrun; m5[1] = O[0]; m5[2] = O[1]; m5[3] = O[2]; m5[4] = O[3];
        }
    }

    // ---- flash merge of the two key-halves, then output ----
    __syncthreads();
    if (w < 4 && g == 0) {
        const float* A = &mrg[w][col][0];
        const float* B = &mrg[w + 4][col][0];
        float o0 = 0.f, o1 = 0.f, o2 = 0.f;
#pragma unroll
        for (int p = 0; p < 2; ++p) {
            const float wgt = p ? 0.2f : 0.8f;
            const float ma = A[p * 5], mb = B[p * 5];
            const float m = fmaxf(ma, mb);
            const float ea = __builtin_amdgcn_exp2f(ma - m);
            const float eb = __builtin_amdgcn_exp2f(mb - m);
            const float l = A[p * 5 + 4] * ea + B[p * 5 + 4] * eb;
            const float inv = wgt / l;
            o0 += (A[p * 5 + 1] * ea + B[p * 5 + 1] * eb) * inv;
            o1 += (A[p * 5 + 2] * ea + B[p * 5 + 2] * eb) * inv;
            o2 += (A[p * 5 + 3] * ea + B[p * 5 + 3] * eb) * inv;
        }
        const int q = qblk * 64 + w * 16 + col;
        float* op = OUT + (((size_t)b * 7 + t) * 4096 + (size_t)q) * 3;
        op[0] = o0; op[1] = o1; op[2] = o2;
    }
}

// ---------------- Fallback (round-4 kernel, known-good) if ws too small ----------------
__global__ __launch_bounds__(256) void kast_attn_fb(
    const float* __restrict__ K, const float* __restrict__ V,
    const float* __restrict__ MK, const float* __restrict__ MV,
    float* __restrict__ OUT)
{
    __shared__ alignas(16) __fp16 sK[2][64][64];
    __shared__ alignas(16) __fp16 sVT[2][4][68];

    const int id = blockIdx.x;
    const int sw = (id & 7) * 112 + (id >> 3);
    const int bt = sw >> 6;
    const int qblk = sw & 63;
    const int b = bt / 7, t = bt % 7;

    const int tid = threadIdx.x;
    const int lane = tid & 63;
    const int w = tid >> 6;
    const int col = lane & 15;
    const int g = lane >> 4;

    const int r = tid >> 2;
    const int c0 = (tid & 3) * 16;
    const int rs = (r & 7) << 3;
    const unsigned vr = (unsigned)tid / 3u;
    const unsigned vd = (unsigned)tid - vr * 3u;

    if (tid < 128) sVT[tid >> 6][3][tid & 63] = (__fp16)1.0f;

    const float* Qbase = K + (((size_t)b * 8 + (t + 1)) * 4096) * 64;
    h8 aq[2];
    {
        const int qrow = qblk * 64 + w * 16 + col;
        const float* qp = Qbase + (size_t)qrow * 64;
#pragma unroll
        for (int ch = 0; ch < 2; ++ch) {
            const int cc = ch * 32 + g * 8;
            const f32x4 xa = *(const f32x4*)&qp[cc];
            const f32x4 xb = *(const f32x4*)&qp[cc + 4];
            const h2 p0 = pkrtz(xa[0] * LOG2E, xa[1] * LOG2E);
            const h2 p1 = pkrtz(xa[2] * LOG2E, xa[3] * LOG2E);
            const h2 p2 = pkrtz(xb[0] * LOG2E, xb[1] * LOG2E);
            const h2 p3 = pkrtz(xb[2] * LOG2E, xb[3] * LOG2E);
            aq[ch] = (h8){p0[0], p0[1], p1[0], p1[1], p2[0], p2[1], p3[0], p3[1]};
        }
    }

    float outc0 = 0.f, outc1 = 0.f, outc2 = 0.f;

    for (int phase = 0; phase < 2; ++phase) {
        const float* kp; const float* vp; int ntile; float wgt;
        if (phase == 0) {
            kp = K + (((size_t)b * 8 + t) * 4096) * 64;
            vp = V + (((size_t)b * 8 + t) * 4096) * 3;
            ntile = 64; wgt = 0.8f;
        } else {
            kp = MK + (((size_t)b * 7 + t) * 1024) * 64;
            vp = MV + (((size_t)b * 7 + t) * 1024) * 3;
            ntile = 16; wgt = 0.2f;
        }
        {
            const float* src = kp + ((size_t)r) * 64 + c0;
            const f32x4* s4 = (const f32x4*)src;
            const f32x4 ra = s4[0], rb = s4[1], rc = s4[2], rd = s4[3];
            const h2 q0 = pkrtz(ra[0], ra[1]), q1 = pkrtz(ra[2], ra[3]);
            const h2 q2 = pkrtz(rb[0], rb[1]), q3 = pkrtz(rb[2], rb[3]);
            const h2 q4 = pkrtz(rc[0], rc[1]), q5 = pkrtz(rc[2], rc[3]);
            const h2 q6 = pkrtz(rd[0], rd[1]), q7 = pkrtz(rd[2], rd[3]);
            *(h8*)&sK[0][r][c0 ^ rs] = (h8){q0[0], q0[1], q1[0], q1[1], q2[0], q2[1], q3[0], q3[1]};
            *(h8*)&sK[0][r][(c0 + 8) ^ rs] = (h8){q4[0], q4[1], q5[0], q5[1], q6[0], q6[1], q7[0], q7[1]};
            if (tid < 192) sVT[0][vd][vr] = (__fp16)vp[tid];
        }
        __syncthreads();

        float mrun = -1e30f;
        f32x4 O = (f32x4){0.f, 0.f, 0.f, 0.f};

        for (int kt = 0; kt < ntile; ++kt) {
            const int cur = kt & 1;
            const bool have = (kt + 1) < ntile;
            f32x4 ra, rb, rc, rd; float rv = 0.f;
            if (have) {
                const float* src = kp + ((size_t)(kt + 1) * 64 + r) * 64 + c0;
                const f32x4* s4 = (const f32x4*)src;
                ra = s4[0]; rb = s4[1]; rc = s4[2]; rd = s4[3];
                if (tid < 192) rv = vp[(size_t)(kt + 1) * 192 + tid];
            }
            f32x4 acc[4];
#pragma unroll
            for (int nt = 0; nt < 4; ++nt) acc[nt] = (f32x4){0.f, 0.f, 0.f, 0.f};
#pragma unroll
            for (int ch = 0; ch < 2; ++ch) {
                h8 bh[4];
#pragma unroll
                for (int nt = 0; nt < 4; ++nt) {
                    const int rr = nt * 16 + col;
                    const int cc = (ch * 32 + g * 8) ^ ((rr & 7) << 3);
                    bh[nt] = *(const h8*)&sK[cur][rr][cc];
                }
#pragma unroll
                for (int nt = 0; nt < 4; ++nt)
                    acc[nt] = __builtin_amdgcn_mfma_f32_16x16x32_f16(bh[nt], aq[ch], acc[nt], 0, 0, 0);
            }
            {
                float tm = acc[0][0];
#pragma unroll
                for (int nt = 0; nt < 4; ++nt)
#pragma unroll
                    for (int j = 0; j < 4; ++j) tm = fmaxf(tm, acc[nt][j]);
                tm = fmaxf(tm, __shfl_xor(tm, 16));
                tm = fmaxf(tm, __shfl_xor(tm, 32));
                if (!__all(tm <= mrun)) {
                    const float mnew = fmaxf(mrun, tm);
                    const float sc = __builtin_amdgcn_exp2f(mrun - mnew);
                    O *= sc;
                    mrun = mnew;
                }
            }
#pragma unroll
            for (int nt = 0; nt < 4; ++nt) {
                const float p0 = __builtin_amdgcn_exp2f(acc[nt][0] - mrun);
                const float p1 = __builtin_amdgcn_exp2f(acc[nt][1] - mrun);
                const float p2 = __builtin_amdgcn_exp2f(acc[nt][2] - mrun);
                const float p3 = __builtin_amdgcn_exp2f(acc[nt][3] - mrun);
                const h2 pa = pkrtz(p0, p1), pb = pkrtz(p2, p3);
                const h4 pf = (h4){pa[0], pa[1], pb[0], pb[1]};
                const h4 vf = *(const h4*)&sVT[cur][col & 3][nt * 16 + 4 * g];
                O = __builtin_amdgcn_mfma_f32_16x16x16f16(vf, pf, O, 0, 0, 0);
            }
            if (have) {
                const int nb = cur ^ 1;
                const h2 q0 = pkrtz(ra[0], ra[1]), q1 = pkrtz(ra[2], ra[3]);
                const h2 q2 = pkrtz(rb[0], rb[1]), q3 = pkrtz(rb[2], rb[3]);
                const h2 q4 = pkrtz(rc[0], rc[1]), q5 = pkrtz(rc[2], rc[3]);
                const h2 q6 = pkrtz(rd[0], rd[1]), q7 = pkrtz(rd[2], rd[3]);
                *(h8*)&sK[nb][r][c0 ^ rs] = (h8){q0[0], q0[1], q1[0], q1[1], q2[0], q2[1], q3[0], q3[1]};
                *(h8*)&sK[nb][r][(c0 + 8) ^ rs] = (h8){q4[0], q4[1], q5[0], q5[1], q6[0], q6[1], q7[0], q7[1]};
                if (tid < 192) sVT[nb][vd][vr] = (__fp16)rv;
            }
            __syncthreads();
        }
        const float inv = wgt / O[3];
        outc0 += O[0] * inv;
        outc1 += O[1] * inv;
        outc2 += O[2] * inv;
    }

    if (g == 0) {
        const int q = qblk * 64 + w * 16 + col;
        float* op = OUT + (((size_t)b * 7 + t) * 4096 + (size_t)q) * 3;
        op[0] = outc0; op[1] = outc1; op[2] = outc2;
    }
}

extern "C" void kernel_launch(void* const* d_in, const int* in_sizes, int n_in,
                              void* d_out, int out_size, void* d_ws, size_t ws_size,
                              hipStream_t stream) {
    const float* K  = (const float*)d_in[0];
    const float* V  = (const float*)d_in[1];
    const float* MK = (const float*)d_in[2];
    const float* MV = (const float*)d_in[3];
    float* OUT = (float*)d_out;
    if (ws_size >= WS_NEED) {
        hipLaunchKernelGGL(kast_pre_kernel, dim3(2520), dim3(256), 0, stream,
                           K, V, MK, MV, (char*)d_ws);
        hipLaunchKernelGGL(kast_attn_kernel, dim3(896), dim3(512), 0, stream,
                           K, (const char*)d_ws, OUT);
    } else {
        hipLaunchKernelGGL(kast_attn_fb, dim3(896), dim3(256), 0, stream,
                           K, V, MK, MV, OUT);
    }
}